// Round 8
// baseline (2223.372 us; speedup 1.0000x reference)
//
#include <hip/hip_runtime.h>

// LSTM: VOCAB=100, INPUT=512, HIDDEN=1024, BATCH=64, SEQ=512
// out = latent[64][512][1024] f32, then h_f[64][1024], c_f[64][1024]
// v8: full-M16 tiles (4bg x 64js, 4 waves/block), gate-interleaved cols with
//     in-wave 4x4 transpose -> wave-local gates, ONE barrier/step, dbuf LDS,
//     8-slot MALL sentinel exchange (v7 protocol), 96KB LDS -> 1 block/CU.

typedef _Float16 f16x8 __attribute__((ext_vector_type(8)));
typedef float    f32x4 __attribute__((ext_vector_type(4)));
typedef unsigned int u32x4 __attribute__((ext_vector_type(4)));
typedef unsigned int u32x2 __attribute__((ext_vector_type(2)));

#define VOCABN 100
#define SENTW 0xFEFEFEFEu   // fp16 0xFEFE = NaN; |h|<1 can never encode as NaN

// ---------------- K0: zx_table[v][g*1024+n] = emb[v] . Wg[n,0:512] + b_g[n] ----------------
__global__ void k0_zxtable(const float* __restrict__ emb,
                           const float* __restrict__ Wf, const float* __restrict__ bf,
                           const float* __restrict__ Wi, const float* __restrict__ bi,
                           const float* __restrict__ Wo, const float* __restrict__ bo,
                           const float* __restrict__ Wg, const float* __restrict__ bg_,
                           float* __restrict__ zx) {
  const int bid = blockIdx.x;            // 256 blocks: (gate, 16-unit chunk)
  const int g = bid >> 6, chunk = bid & 63;
  const float* W = (g==0)?Wf:(g==1)?Wi:(g==2)?Wo:Wg;
  const float* B = (g==0)?bf:(g==1)?bi:(g==2)?bo:bg_;
  __shared__ float Wl[16][516];
  const int tid = threadIdx.x;
  for (int i = tid; i < 2048; i += 256) {
    int r = i >> 7, c4 = i & 127;
    float4 v = *(const float4*)&W[(size_t)(chunk*16 + r)*1536 + c4*4];
    Wl[r][c4*4+0]=v.x; Wl[r][c4*4+1]=v.y; Wl[r][c4*4+2]=v.z; Wl[r][c4*4+3]=v.w;
  }
  __syncthreads();
  const int u = tid & 15, vi = tid >> 4;
  for (int v0 = 0; v0 < VOCABN; v0 += 16) {
    int v = v0 + vi;
    if (v < VOCABN) {
      const float* er = emb + (size_t)v*512;
      float acc = 0.f;
      #pragma unroll 8
      for (int k = 0; k < 512; k++) acc += er[k]*Wl[u][k];
      zx[(size_t)v*4096 + g*1024 + chunk*16 + u] = acc + B[chunk*16 + u];
    }
  }
}

// ---------------- K1: Whh fp16 conversion + h0 -> hstage slot 7 ----------------
__global__ void k1_prep(const float* __restrict__ Wf, const float* __restrict__ Wi,
                        const float* __restrict__ Wo, const float* __restrict__ Wg,
                        const float* __restrict__ h0,
                        _Float16* __restrict__ Whh, _Float16* __restrict__ hstage) {
  const int bid = blockIdx.x, tid = threadIdx.x;
  if (bid < 1024) {
    #pragma unroll
    for (int i = 0; i < 4; i++) {
      int F = bid*1024 + i*256 + tid;            // float4 index, 2^20 total
      int g = F >> 18;
      int rem = F & ((1<<18)-1);
      int n = rem >> 8, k4 = rem & 255;
      const float* W = (g==0)?Wf:(g==1)?Wi:(g==2)?Wo:Wg;
      float4 v = *(const float4*)&W[(size_t)n*1536 + 512 + k4*4];
      _Float16 h4[4] = {(_Float16)v.x,(_Float16)v.y,(_Float16)v.z,(_Float16)v.w};
      *(unsigned long long*)&Whh[((size_t)g<<20) + (n<<10) + (k4<<2)] =
          *(unsigned long long*)h4;
    }
  } else {
    int j = bid - 1024;                          // 64 blocks: h0 -> slot 7 (= (0-1)&7)
    int base = j*1024 + tid*4;
    float4 v = *(const float4*)&h0[base];
    _Float16 h4[4] = {(_Float16)v.x,(_Float16)v.y,(_Float16)v.z,(_Float16)v.w};
    *(unsigned long long*)&hstage[7*65536 + base] = *(unsigned long long*)h4;
  }
}

// ---------------- Main persistent LSTM: 256 blocks = 4 bg x 64 js, 256 thr ----------------
__global__ __launch_bounds__(256, 1) void lstm_main(
    const int* __restrict__ X, const float* __restrict__ c0,
    const float* __restrict__ zx, const _Float16* __restrict__ Whh,
    _Float16* __restrict__ hstage, float* out)
{
  extern __shared__ char smem[];        // [2][32KB] A-tile double buffer (+pad)
  const int bid = blockIdx.x;
  const int bg  = bid >> 6;             // batch group: 16 batches
  const int js  = bid & 63;             // unit slice: 16 units (x4 gates = 64 cols)
  const int tid = threadIdx.x;
  const int w   = tid >> 6;             // wave 0..3: units js*16+w*4 .. +4
  const int l   = tid & 63;
  const int lm  = l & 15, lh = l >> 4;

  // ---- weights: col c=lm -> unit js*16+w*4+(c>>2), gate c&3; pinned via asm ----
  f16x8 bw[32];
  {
    const _Float16* wp = Whh + ((size_t)(lm&3)<<20)
                       + ((size_t)(js*16 + w*4 + (lm>>2))<<10) + (lh<<3);
    #pragma unroll
    for (int kk = 0; kk < 32; kk++) {
      asm volatile("global_load_dwordx4 %0, %1, off"
                   : "=&v"(bw[kk]) : "v"(wp + kk*32));
    }
    asm volatile("s_waitcnt vmcnt(0)");
    __builtin_amdgcn_sched_barrier(0);
  }

  // staging: thread (sr = tid&15, q = tid>>4): row bg*16+sr, bytes q*128..+128
  // (= chunks kk=2q,2q+1); LDS layout [kk][ks:4][row:16][16B]
  const int sr = tid & 15, q = tid >> 4;
  const unsigned sgoff = (unsigned)((bg*16 + sr)*2048 + q*128);
  const int lwoff = q*2048 + sr*16;               // + ks*256 (+1024 for kk=2q+1)
  const int hboff = l*16;                         // read: + kk*1024 (ks=lh,row=lm)

  // gate-lane role: every lane owns (batch b, unit ucol)
  const int b    = 4*lh + (lm & 3);
  const int brow = bg*16 + b;
  const int ucol = js*16 + w*4 + (lm >> 2);
  float c = c0[(size_t)brow*1024 + ucol];
  const int* Xr = X + (size_t)brow*512;
  float* latp = out + (size_t)brow*512*1024 + ucol;
  const unsigned pub_off = (unsigned)(brow*2048 + (js*16 + w*4)*2);  // 8B row-chunk
  const int g0 = lm & 1, g1 = (lm >> 1) & 1;

  // zx for t=0
  float zc0, zc1, zc2, zc3;
  {
    int xv = Xr[0];
    const float* p = zx + (size_t)xv*4096 + ucol;
    zc0 = p[0]; zc1 = p[1024]; zc2 = p[2048]; zc3 = p[3072];
  }

  for (int t = 0; t < 512; t++) {
    // ---- prefetch next step's token contribution ----
    float zn0=0.f, zn1=0.f, zn2=0.f, zn3=0.f;
    if (t < 511) {
      int xv = Xr[t+1];
      const float* p = zx + (size_t)xv*4096 + ucol;
      zn0 = p[0]; zn1 = p[1024]; zn2 = p[2048]; zn3 = p[3072];
    }

    // ---- stage h_{t-1} from slot (t-1)&7: sc1 sentinel-polled 128B/thread ----
    char* sbuf = smem + (t & 1)*32768;
    {
      const char* sb = (const char*)hstage + ((unsigned)((t+7)&7) << 17) + sgoff;
      u32x4 v0,v1,v2,v3,v4,v5,v6,v7;
      int spin = 0;
      for (;;) {
        asm volatile(
          "global_load_dwordx4 %0, %8, off sc1\n\t"
          "global_load_dwordx4 %1, %8, off offset:16 sc1\n\t"
          "global_load_dwordx4 %2, %8, off offset:32 sc1\n\t"
          "global_load_dwordx4 %3, %8, off offset:48 sc1\n\t"
          "global_load_dwordx4 %4, %8, off offset:64 sc1\n\t"
          "global_load_dwordx4 %5, %8, off offset:80 sc1\n\t"
          "global_load_dwordx4 %6, %8, off offset:96 sc1\n\t"
          "global_load_dwordx4 %7, %8, off offset:112 sc1\n\t"
          "s_waitcnt vmcnt(0)"
          : "=&v"(v0),"=&v"(v1),"=&v"(v2),"=&v"(v3),
            "=&v"(v4),"=&v"(v5),"=&v"(v6),"=&v"(v7)
          : "v"(sb));
        #define BAD4(vv) ((vv.x==SENTW)|(vv.y==SENTW)|(vv.z==SENTW)|(vv.w==SENTW))
        bool bad = BAD4(v0)|BAD4(v1)|BAD4(v2)|BAD4(v3)
                 | BAD4(v4)|BAD4(v5)|BAD4(v6)|BAD4(v7);
        #undef BAD4
        if (!bad || ++spin > (1<<16)) break;      // bounded: fail clean, never hang
      }
      char* wp0 = sbuf + lwoff;
      *(u32x4*)(wp0 +    0) = v0;  *(u32x4*)(wp0 +  256) = v1;
      *(u32x4*)(wp0 +  512) = v2;  *(u32x4*)(wp0 +  768) = v3;
      *(u32x4*)(wp0 + 1024) = v4;  *(u32x4*)(wp0 + 1280) = v5;
      *(u32x4*)(wp0 + 1536) = v6;  *(u32x4*)(wp0 + 1792) = v7;
    }
    __syncthreads();   // the ONLY barrier per step

    // ---- MFMA: z[16b x 16cols] per wave, K=1024 ----
    const char* hb = sbuf + hboff;
    f32x4 a0={0,0,0,0}, a1={0,0,0,0}, a2={0,0,0,0}, a3={0,0,0,0};
    #pragma unroll
    for (int kk = 0; kk < 32; kk += 4) {
      f16x8 x0 = *(const f16x8*)(hb + (kk+0)*1024);
      f16x8 x1 = *(const f16x8*)(hb + (kk+1)*1024);
      f16x8 x2 = *(const f16x8*)(hb + (kk+2)*1024);
      f16x8 x3 = *(const f16x8*)(hb + (kk+3)*1024);
      a0 = __builtin_amdgcn_mfma_f32_16x16x32_f16(x0, bw[kk+0], a0, 0, 0, 0);
      a1 = __builtin_amdgcn_mfma_f32_16x16x32_f16(x1, bw[kk+1], a1, 0, 0, 0);
      a2 = __builtin_amdgcn_mfma_f32_16x16x32_f16(x2, bw[kk+2], a2, 0, 0, 0);
      a3 = __builtin_amdgcn_mfma_f32_16x16x32_f16(x3, bw[kk+3], a3, 0, 0, 0);
    }
    f32x4 z4 = (a0 + a1) + (a2 + a3);

    // ---- in-wave 4x4 transpose (lane group = 4 gate-cols of one unit) ----
    // before: lane (g = lm&3) holds rows 4lh+r of gate g.  after: lane (j = lm&3)
    // holds all 4 gates of row 4lh+j.
    float v0 = z4[0], v1 = z4[1], v2 = z4[2], v3 = z4[3];
    float alo = g0 ? v0 : v1,  ahi = g0 ? v2 : v3;
    float s0 = __shfl_xor(alo, 1), s1 = __shfl_xor(ahi, 1);
    float n0 = g0 ? s0 : v0,  n1 = g0 ? v1 : s0;
    float n2 = g0 ? s1 : v2,  n3 = g0 ? v3 : s1;
    float blo = g1 ? n0 : n2, bhi = g1 ? n1 : n3;
    float t0 = __shfl_xor(blo, 2), t1 = __shfl_xor(bhi, 2);
    float wf = g1 ? t0 : n0,  wo = g1 ? n2 : t0;
    float wi = g1 ? t1 : n1,  wg = g1 ? n3 : t1;

    // ---- gates + state update (all 64 lanes productive) ----
    float zf = wf + zc0, zi = wi + zc1, zo = wo + zc2, zg = wg + zc3;
    float fg = 1.f/(1.f + __expf(-zf));
    float ig = 1.f/(1.f + __expf(-zi));
    float og = 1.f/(1.f + __expf(-zo));
    float e2g = __expf(2.f*zg);
    float gg = 1.f - 2.f/(e2g + 1.f);
    c = fg*c + ig*gg;
    float e2c = __expf(2.f*c);
    float h = og*(1.f - 2.f/(e2c + 1.f));

    // ---- publish: pack 4 units of this row -> 8B sc1 store (lanes lm<4) ----
    if (t < 511) {
      unsigned hu = (unsigned)__builtin_bit_cast(unsigned short, (_Float16)h);
      unsigned p4 = (unsigned)__shfl_xor((int)hu, 4);
      unsigned pair = (lm & 4) ? ((p4 & 0xffffu) | (hu << 16))
                               : ((hu & 0xffffu) | (p4 << 16));
      unsigned hi = (unsigned)__shfl_xor((int)pair, 8);
      if ((lm & 12) == 0) {
        u32x2 pk; pk[0] = pair; pk[1] = hi;       // units u0,u1 | u2,u3
        char* pb = (char*)hstage + ((unsigned)(t & 7) << 17) + pub_off;
        asm volatile("global_store_dwordx2 %0, %1, off sc1"
                     :: "v"(pb), "v"(pk) : "memory");
        if (t <= 506) {                            // re-sentinel slot (t+4)&7
          u32x2 sv; sv[0] = SENTW; sv[1] = SENTW;
          char* rb = (char*)hstage + ((unsigned)((t+4) & 7) << 17) + pub_off;
          asm volatile("global_store_dwordx2 %0, %1, off sc1"
                       :: "v"(rb), "v"(sv) : "memory");
        }
      }
    }

    // ---- latent output (off critical path; drains under next poll/barrier) ----
    __builtin_nontemporal_store(h, latp + (size_t)t*1024);
    if (t == 511) {
      out[33554432 + ((size_t)brow<<10) + ucol] = h;   // h_f
      out[33619968 + ((size_t)brow<<10) + ucol] = c;   // c_f
    }
    zc0 = zn0; zc1 = zn1; zc2 = zn2; zc3 = zn3;
  }
}

extern "C" void kernel_launch(void* const* d_in, const int* in_sizes, int n_in,
                              void* d_out, int out_size, void* d_ws, size_t ws_size,
                              hipStream_t stream) {
  const int*   X   = (const int*)  d_in[0];
  const float* h0  = (const float*)d_in[1];
  const float* c0  = (const float*)d_in[2];
  const float* emb = (const float*)d_in[3];
  const float* Wf  = (const float*)d_in[4];  const float* bf = (const float*)d_in[5];
  const float* Wi  = (const float*)d_in[6];  const float* bi = (const float*)d_in[7];
  const float* Wo  = (const float*)d_in[8];  const float* bo = (const float*)d_in[9];
  const float* Wg  = (const float*)d_in[10]; const float* bg = (const float*)d_in[11];
  float* out = (float*)d_out;

  char* ws = (char*)d_ws;
  float*    zx     = (float*)   ws;                          // 1,638,400 B
  _Float16* Whh    = (_Float16*)(ws + 1638400);              // 8,388,608 B
  _Float16* hstage = (_Float16*)(ws + 1638400 + 8388608);    // 8 slots * 131,072 B

  hipMemsetAsync(hstage, 0xFE, 8*131072, stream);            // NaN-sentinel all slots
  k0_zxtable<<<256, 256, 0, stream>>>(emb, Wf, bf, Wi, bi, Wo, bo, Wg, bg, zx);
  k1_prep<<<1088, 256, 0, stream>>>(Wf, Wi, Wo, Wg, h0, Whh, hstage);
  // 96KB dynamic LDS: 2x32KB A-buffers + pad to force exactly 1 block/CU
  lstm_main<<<256, 256, 98304, stream>>>(X, c0, zx, Whh, hstage, out);
}

// Round 9
// 1700.277 us; speedup vs baseline: 1.3077x; 1.3077x over previous
//
#include <hip/hip_runtime.h>

// LSTM: VOCAB=100, INPUT=512, HIDDEN=1024, BATCH=64, SEQ=512
// out = latent[64][512][1024] f32, then h_f[64][1024], c_f[64][1024]
// v9: v7 structure + flag-gated exchange with write-once step slots.
//     Producers: 16B sc1 publish -> vmcnt drain -> barrier -> 4B sc1 flag.
//     Consumers: poll own producer's flag (4B sc1), then PLAIN CACHED data
//     loads (write-once lines -> L2 multicast absorbs the 32x fan-out).
//     Fallback (small ws): 8 rotating slots + sc1 data loads (still flag-gated).

typedef _Float16 f16x8 __attribute__((ext_vector_type(8)));
typedef float    f32x4 __attribute__((ext_vector_type(4)));
typedef unsigned int u32x4 __attribute__((ext_vector_type(4)));

#define VOCABN 100

// ---------------- K0: zx_table[v][g*1024+n] = emb[v] . Wg[n,0:512] + b_g[n] ----------------
__global__ void k0_zxtable(const float* __restrict__ emb,
                           const float* __restrict__ Wf, const float* __restrict__ bf,
                           const float* __restrict__ Wi, const float* __restrict__ bi,
                           const float* __restrict__ Wo, const float* __restrict__ bo,
                           const float* __restrict__ Wg, const float* __restrict__ bg_,
                           float* __restrict__ zx) {
  const int bid = blockIdx.x;            // 256 blocks: (gate, 16-unit chunk)
  const int g = bid >> 6, chunk = bid & 63;
  const float* W = (g==0)?Wf:(g==1)?Wi:(g==2)?Wo:Wg;
  const float* B = (g==0)?bf:(g==1)?bi:(g==2)?bo:bg_;
  __shared__ float Wl[16][516];
  const int tid = threadIdx.x;
  for (int i = tid; i < 2048; i += 256) {
    int r = i >> 7, c4 = i & 127;
    float4 v = *(const float4*)&W[(size_t)(chunk*16 + r)*1536 + c4*4];
    Wl[r][c4*4+0]=v.x; Wl[r][c4*4+1]=v.y; Wl[r][c4*4+2]=v.z; Wl[r][c4*4+3]=v.w;
  }
  __syncthreads();
  const int u = tid & 15, vi = tid >> 4;
  for (int v0 = 0; v0 < VOCABN; v0 += 16) {
    int v = v0 + vi;
    if (v < VOCABN) {
      const float* er = emb + (size_t)v*512;
      float acc = 0.f;
      #pragma unroll 8
      for (int k = 0; k < 512; k++) acc += er[k]*Wl[u][k];
      zx[(size_t)v*4096 + g*1024 + chunk*16 + u] = acc + B[chunk*16 + u];
    }
  }
}

// ---------------- K1: Whh fp16 conversion + h0 -> h0slot ----------------
__global__ void k1_prep(const float* __restrict__ Wf, const float* __restrict__ Wi,
                        const float* __restrict__ Wo, const float* __restrict__ Wg,
                        const float* __restrict__ h0,
                        _Float16* __restrict__ Whh, _Float16* __restrict__ h0slot) {
  const int bid = blockIdx.x, tid = threadIdx.x;
  if (bid < 1024) {
    #pragma unroll
    for (int i = 0; i < 4; i++) {
      int F = bid*1024 + i*256 + tid;            // float4 index, 2^20 total
      int g = F >> 18;
      int rem = F & ((1<<18)-1);
      int n = rem >> 8, k4 = rem & 255;
      const float* W = (g==0)?Wf:(g==1)?Wi:(g==2)?Wo:Wg;
      float4 v = *(const float4*)&W[(size_t)n*1536 + 512 + k4*4];
      _Float16 h4[4] = {(_Float16)v.x,(_Float16)v.y,(_Float16)v.z,(_Float16)v.w};
      *(unsigned long long*)&Whh[((size_t)g<<20) + (n<<10) + (k4<<2)] =
          *(unsigned long long*)h4;
    }
  } else {
    int j = bid - 1024;                          // 64 blocks: h0 -> the t=-1 slot
    int base = j*1024 + tid*4;
    float4 v = *(const float4*)&h0[base];
    _Float16 h4[4] = {(_Float16)v.x,(_Float16)v.y,(_Float16)v.z,(_Float16)v.w};
    *(unsigned long long*)&h0slot[base] = *(unsigned long long*)h4;
  }
}

// ---------------- Main persistent LSTM: 256 blocks = 8 bg x 32 js, 512 thr ----------------
template<bool CACHED>
__global__ __launch_bounds__(512, 1) void lstm_main(
    const int* __restrict__ X, const float* __restrict__ c0,
    const float* __restrict__ zx, const _Float16* __restrict__ Whh,
    _Float16* __restrict__ hstage, int* __restrict__ flags, float* out)
{
  constexpr unsigned SLOT_MASK = CACHED ? 511u : 7u;
  const int bid = blockIdx.x;
  const int bg  = bid & 7;             // batch group (XCD round-robin heuristic)
  const int js  = bid >> 3;            // unit slice: 32 units (x4 gates = 128 cols)
  const int tid = threadIdx.x;
  const int w   = tid >> 6;            // wave 0..7
  const int l   = tid & 63;
  const int lm = l & 15, lh = l >> 4;

  __shared__ alignas(16) _Float16 hs[16384];      // 32 kk-chunks x 1KB, fragment order
  __shared__ float zsh[8][132];                   // z exchange [batch][4*32 cols]

  // ---- weights: asm loads -> pinned residency (gate=w>>1, half=w&1) ----
  f16x8 bw[32];
  {
    const _Float16* wp = Whh + ((size_t)(w>>1)<<20)
                       + ((size_t)(js*32 + (w&1)*16 + lm)<<10) + (lh<<3);
    #pragma unroll
    for (int kk = 0; kk < 32; kk++) {
      asm volatile("global_load_dwordx4 %0, %1, off"
                   : "=&v"(bw[kk]) : "v"(wp + kk*32));
    }
    asm volatile("s_waitcnt vmcnt(0)");
    __builtin_amdgcn_sched_barrier(0);
  }

  // staging role: thread covers chunk kk=4w+lh (= producer js), row l&7,
  // kslot-pair kp=(l>>3)&1 (32B). Rows 8-15 of each chunk stay garbage.
  const int kk  = 4*w + lh;
  const int srw = l & 7;
  const int kp  = (l >> 3) & 1;
  const unsigned sgoff = (unsigned)((bg*8 + srw)*2048 + kk*64 + kp*32);
  char* lw = (char*)hs + kk*1024 + kp*512 + srw*16;
  const char* hb = (const char*)hs + (l << 4);        // MFMA read base

  // gate-phase role (tid<256): one (batch b, unit u)
  const int b = (tid >> 5) & 7, u = tid & 31;
  const int brow = bg*8 + b, ucol = js*32 + u;
  float c = 0.f, hkeep = 0.f;
  const int* Xr = nullptr;
  if (tid < 256) {
    c = c0[(size_t)brow*1024 + ucol];
    Xr = X + (size_t)brow*512;
  }
  float* latp = out + (size_t)brow*512*1024 + ucol;
  const unsigned pboff = (unsigned)(brow*2048 + (js*32 + (u & 24))*2);

  // zx for t=0 (prefetched one step ahead thereafter)
  float zc0=0.f, zc1=0.f, zc2=0.f, zc3=0.f;
  if (tid < 256) {
    int xv = Xr[0];
    const float* p = zx + (size_t)xv*4096 + ucol;
    zc0 = p[0]; zc1 = p[1024]; zc2 = p[2048]; zc3 = p[3072];
  }

  for (int t = 0; t < 512; t++) {
    // ---- prefetch next step's token contribution ----
    float zn0=0.f, zn1=0.f, zn2=0.f, zn3=0.f;
    if (tid < 256 && t < 511) {
      int xv = Xr[t+1];
      const float* p = zx + (size_t)xv*4096 + ucol;
      zn0 = p[0]; zn1 = p[1024]; zn2 = p[2048]; zn3 = p[3072];
    }

    // ---- stage h_{t-1} from slot (t-1)&MASK: flag-gated ----
    u32x4 va, vb;
    {
      if (t > 0) {
        // poll ONLY my producer's flag (4B sc1); write-once -> no retries after set
        const int* fp = flags + (t-1)*256 + bg*32 + kk;
        int f, spin = 0;
        do {
          asm volatile("global_load_dword %0, %1, off sc1\n\t"
                       "s_waitcnt vmcnt(0)" : "=v"(f) : "v"(fp));
        } while (f == 0 && ++spin < (1<<16));    // bounded: fail clean, never hang
      }
      const char* sb = (const char*)hstage
                     + ((size_t)((unsigned)(t+511) & SLOT_MASK) << 17) + sgoff;
      if constexpr (CACHED) {
        // plain cached loads: line written once ever -> any L1/L2 hit is final data
        asm volatile(
          "global_load_dwordx4 %0, %2, off\n\t"
          "global_load_dwordx4 %1, %2, off offset:16\n\t"
          "s_waitcnt vmcnt(0)"
          : "=&v"(va), "=&v"(vb) : "v"(sb));
      } else {
        asm volatile(
          "global_load_dwordx4 %0, %2, off sc1\n\t"
          "global_load_dwordx4 %1, %2, off offset:16 sc1\n\t"
          "s_waitcnt vmcnt(0)"
          : "=&v"(va), "=&v"(vb) : "v"(sb));
      }
    }
    *(u32x4*)(lw)       = va;
    *(u32x4*)(lw + 256) = vb;
    __syncthreads();   // S1

    // ---- MFMA: z[16x16] per wave, K=1024, lane-linear conflict-free reads ----
    f32x4 a0={0,0,0,0}, a1={0,0,0,0}, a2={0,0,0,0}, a3={0,0,0,0};
    #pragma unroll
    for (int k2 = 0; k2 < 32; k2 += 4) {
      f16x8 x0 = *(const f16x8*)(hb + (k2+0)*1024);
      f16x8 x1 = *(const f16x8*)(hb + (k2+1)*1024);
      f16x8 x2 = *(const f16x8*)(hb + (k2+2)*1024);
      f16x8 x3 = *(const f16x8*)(hb + (k2+3)*1024);
      a0 = __builtin_amdgcn_mfma_f32_16x16x32_f16(x0, bw[k2+0], a0, 0, 0, 0);
      a1 = __builtin_amdgcn_mfma_f32_16x16x32_f16(x1, bw[k2+1], a1, 0, 0, 0);
      a2 = __builtin_amdgcn_mfma_f32_16x16x32_f16(x2, bw[k2+2], a2, 0, 0, 0);
      a3 = __builtin_amdgcn_mfma_f32_16x16x32_f16(x3, bw[k2+3], a3, 0, 0, 0);
    }
    f32x4 z4 = (a0 + a1) + (a2 + a3);
    if (lh < 2) {                      // D rows 0..7 (real batches): row=lh*4+r, col=lm
      #pragma unroll
      for (int r4 = 0; r4 < 4; r4++)
        zsh[lh*4 + r4][(w>>1)*32 + (w&1)*16 + lm] = z4[r4];
    }
    __syncthreads();   // S2

    // ---- gates + state update + publish (16B sc1, full-line coalesced) ----
    if (tid < 256) {
      float zf = zsh[b][u]      + zc0;
      float zi = zsh[b][32+u]   + zc1;
      float zo = zsh[b][64+u]   + zc2;
      float zg = zsh[b][96+u]   + zc3;
      float fg = 1.f/(1.f + __expf(-zf));
      float ig = 1.f/(1.f + __expf(-zi));
      float og = 1.f/(1.f + __expf(-zo));
      float e2g = __expf(2.f*zg);
      float gg = 1.f - 2.f/(e2g + 1.f);
      c = fg*c + ig*gg;
      float e2c = __expf(2.f*c);
      hkeep = og*(1.f - 2.f/(e2c + 1.f));

      // latent store here: drains at S3 together with publish (off S1 path)
      __builtin_nontemporal_store(hkeep, latp + (size_t)t*1024);

      if (t < 511) {
        // butterfly-pack 8 consecutive units' fp16 into one 16B chunk
        unsigned hu = (unsigned)__builtin_bit_cast(unsigned short, (_Float16)hkeep);
        unsigned o1 = (unsigned)__shfl_xor((int)hu, 1);
        unsigned d  = (l & 1) ? ((o1 & 0xffffu) | (hu << 16))
                              : ((hu & 0xffffu) | (o1 << 16));
        unsigned o2 = (unsigned)__shfl_xor((int)d, 2);
        unsigned q0 = (l & 2) ? o2 : d;
        unsigned q1 = (l & 2) ? d : o2;
        unsigned o3a = (unsigned)__shfl_xor((int)q0, 4);
        unsigned o3b = (unsigned)__shfl_xor((int)q1, 4);
        u32x4 pk;
        if (l & 4) { pk[0]=o3a; pk[1]=o3b; pk[2]=q0; pk[3]=q1; }
        else       { pk[0]=q0;  pk[1]=q1;  pk[2]=o3a; pk[3]=o3b; }
        if ((l & 7) == 0) {
          char* pb = (char*)hstage + ((size_t)((unsigned)t & SLOT_MASK) << 17) + pboff;
          asm volatile("global_store_dwordx4 %0, %1, off sc1"
                       :: "v"(pb), "v"(pk) : "memory");
        }
      }
    }

    // ---- release: drain all stores, block-wide sync, then set flag ----
    asm volatile("s_waitcnt vmcnt(0)");
    __syncthreads();   // S3: every wave's publish is at the coherence point
    if (tid == 0 && t < 511) {
      const int one = 1;
      asm volatile("global_store_dword %0, %1, off sc1"
                   :: "v"(flags + t*256 + bg*32 + js), "v"(one) : "memory");
    }
    zc0 = zn0; zc1 = zn1; zc2 = zn2; zc3 = zn3;
  }

  if (tid < 256) {
    out[33554432 + ((size_t)brow<<10) + ucol] = hkeep;   // h_f
    out[33619968 + ((size_t)brow<<10) + ucol] = c;       // c_f
  }
}

extern "C" void kernel_launch(void* const* d_in, const int* in_sizes, int n_in,
                              void* d_out, int out_size, void* d_ws, size_t ws_size,
                              hipStream_t stream) {
  const int*   X   = (const int*)  d_in[0];
  const float* h0  = (const float*)d_in[1];
  const float* c0  = (const float*)d_in[2];
  const float* emb = (const float*)d_in[3];
  const float* Wf  = (const float*)d_in[4];  const float* bf = (const float*)d_in[5];
  const float* Wi  = (const float*)d_in[6];  const float* bi = (const float*)d_in[7];
  const float* Wo  = (const float*)d_in[8];  const float* bo = (const float*)d_in[9];
  const float* Wg  = (const float*)d_in[10]; const float* bg = (const float*)d_in[11];
  float* out = (float*)d_out;

  char* ws = (char*)d_ws;
  const size_t base = 1638400 + 8388608;        // zx + Whh
  float*    zx  = (float*)   ws;
  _Float16* Whh = (_Float16*)(ws + 1638400);

  const size_t need_big = base + (size_t)512*131072 + 524288;
  const bool   big      = ws_size >= need_big;
  const size_t nslots   = big ? 512 : 8;
  _Float16* hstage = (_Float16*)(ws + base);
  int*      flags  = (int*)    (ws + base + nslots*131072);
  _Float16* h0slot = hstage + (big ? (size_t)511*65536 : (size_t)7*65536);

  hipMemsetAsync(flags, 0, 524288, stream);
  k0_zxtable<<<256, 256, 0, stream>>>(emb, Wf, bf, Wi, bi, Wo, bo, Wg, bg, zx);
  k1_prep<<<1088, 256, 0, stream>>>(Wf, Wi, Wo, Wg, h0, Whh, h0slot);
  if (big)
    lstm_main<true><<<256, 512, 0, stream>>>(X, c0, zx, Whh, hstage, flags, out);
  else
    lstm_main<false><<<256, 512, 0, stream>>>(X, c0, zx, Whh, hstage, flags, out);
}